// Round 1
// baseline (2823.855 us; speedup 1.0000x reference)
//
#include <hip/hip_runtime.h>
#include <hip/hip_bf16.h>

#define D 128  // EMBED == LAYER == 128

// ---------------------------------------------------------------------------
// Kernel 1: P = item_emb @ W   ([n_items,128] x [128,128] -> [n_items,128])
// W staged in LDS (64 KB). Block = 256 threads; each block does 64 item rows.
// Thread (tid) owns 4 consecutive output columns (c4) for 8 strided rows.
// ---------------------------------------------------------------------------
__global__ __launch_bounds__(256) void pw_kernel(
    const float* __restrict__ emb, const float* __restrict__ W,
    float* __restrict__ P, int n_items) {
  __shared__ float Wlds[D * D];  // 64 KB
  const int tid = threadIdx.x;

  // cooperative load of W: 16384 floats / 256 threads = 16 float4 each
  {
    const float4* W4 = reinterpret_cast<const float4*>(W);
    float4* Wl4 = reinterpret_cast<float4*>(Wlds);
#pragma unroll
    for (int i = 0; i < 16; ++i) Wl4[tid + 256 * i] = W4[tid + 256 * i];
  }
  __syncthreads();

  const int c4 = (tid & 31) * 4;  // column quad
  const int rg = tid >> 5;        // row group 0..7
  const int item0 = blockIdx.x * 64;

  for (int r = item0 + rg; r < item0 + 64; r += 8) {
    if (r >= n_items) break;
    const float4* er4 = reinterpret_cast<const float4*>(emb + (size_t)r * D);
    float4 acc = {0.f, 0.f, 0.f, 0.f};
#pragma unroll
    for (int k4 = 0; k4 < D / 4; ++k4) {
      const float4 e = er4[k4];
      const int kb = k4 * 4;
      {
        const float4 w = *reinterpret_cast<const float4*>(&Wlds[(kb + 0) * D + c4]);
        acc.x += e.x * w.x; acc.y += e.x * w.y; acc.z += e.x * w.z; acc.w += e.x * w.w;
      }
      {
        const float4 w = *reinterpret_cast<const float4*>(&Wlds[(kb + 1) * D + c4]);
        acc.x += e.y * w.x; acc.y += e.y * w.y; acc.z += e.y * w.z; acc.w += e.y * w.w;
      }
      {
        const float4 w = *reinterpret_cast<const float4*>(&Wlds[(kb + 2) * D + c4]);
        acc.x += e.z * w.x; acc.y += e.z * w.y; acc.z += e.z * w.z; acc.w += e.z * w.w;
      }
      {
        const float4 w = *reinterpret_cast<const float4*>(&Wlds[(kb + 3) * D + c4]);
        acc.x += e.w * w.x; acc.y += e.w * w.y; acc.z += e.w * w.z; acc.w += e.w * w.w;
      }
    }
    *reinterpret_cast<float4*>(P + (size_t)r * D + c4) = acc;
  }
}

// ---------------------------------------------------------------------------
// Kernel 2: edge scatter.  out[row] += (val * n_j[row]) * P[col]
// Each edge is handled by 32 lanes (half-wave), 4 floats per lane (float4
// gather of P, 4x atomicAdd into out).
// ---------------------------------------------------------------------------
__global__ __launch_bounds__(256) void scatter_kernel(
    const float* __restrict__ P, const float* __restrict__ vals,
    const int* __restrict__ rows, const int* __restrict__ cols,
    const float* __restrict__ nj, float* __restrict__ out, int n_edges) {
  const long long tid = (long long)blockIdx.x * blockDim.x + threadIdx.x;
  const int e = (int)(tid >> 5);
  if (e >= n_edges) return;
  const int lane = (int)(tid & 31);

  const int r = rows[e];
  const int c = cols[e];
  const float s = vals[e] * nj[r];

  const float4 p =
      *reinterpret_cast<const float4*>(P + (size_t)c * D + lane * 4);
  float* o = out + (size_t)r * D + lane * 4;
  unsafeAtomicAdd(o + 0, s * p.x);
  unsafeAtomicAdd(o + 1, s * p.y);
  unsafeAtomicAdd(o + 2, s * p.z);
  unsafeAtomicAdd(o + 3, s * p.w);
}

extern "C" void kernel_launch(void* const* d_in, const int* in_sizes, int n_in,
                              void* d_out, int out_size, void* d_ws,
                              size_t ws_size, hipStream_t stream) {
  const float* item_emb = (const float*)d_in[0];  // [n_items, 128]
  const float* user_nj  = (const float*)d_in[1];  // [n_users, 1]
  const float* weight   = (const float*)d_in[2];  // [128, 128]
  const float* adj_vals = (const float*)d_in[3];  // [E]
  const int*   adj_rows = (const int*)d_in[4];    // [E]
  const int*   adj_cols = (const int*)d_in[5];    // [E]

  const int n_items = in_sizes[0] / D;
  const int n_edges = in_sizes[3];
  float* out = (float*)d_out;
  float* P = (float*)d_ws;  // [n_items, 128] fp32 = 25.6 MB scratch

  // 1) P = item_emb @ W
  {
    const int blocks = (n_items + 63) / 64;
    pw_kernel<<<blocks, 256, 0, stream>>>(item_emb, weight, P, n_items);
  }

  // 2) zero the output accumulator
  hipMemsetAsync(d_out, 0, (size_t)out_size * sizeof(float), stream);

  // 3) scatter-add edges: out[row] += val * nj[row] * P[col]
  {
    const long long total_threads = (long long)n_edges * 32;
    const int blocks = (int)((total_threads + 255) / 256);
    scatter_kernel<<<blocks, 256, 0, stream>>>(P, adj_vals, adj_rows, adj_cols,
                                               user_nj, out, n_edges);
  }
}

// Round 2
// 605.163 us; speedup vs baseline: 4.6663x; 4.6663x over previous
//
#include <hip/hip_runtime.h>
#include <hip/hip_bf16.h>

#define D 128  // EMBED == LAYER == 128

// ---------------------------------------------------------------------------
// Kernel 1: P = item_emb @ W   ([n_items,128] x [128,128] -> [n_items,128])
// W staged in LDS (64 KB). Block = 256 threads; each block does 64 item rows.
// ---------------------------------------------------------------------------
__global__ __launch_bounds__(256) void pw_kernel(
    const float* __restrict__ emb, const float* __restrict__ W,
    float* __restrict__ P, int n_items) {
  __shared__ float Wlds[D * D];  // 64 KB
  const int tid = threadIdx.x;

  {
    const float4* W4 = reinterpret_cast<const float4*>(W);
    float4* Wl4 = reinterpret_cast<float4*>(Wlds);
#pragma unroll
    for (int i = 0; i < 16; ++i) Wl4[tid + 256 * i] = W4[tid + 256 * i];
  }
  __syncthreads();

  const int c4 = (tid & 31) * 4;  // column quad
  const int rg = tid >> 5;        // row group 0..7
  const int item0 = blockIdx.x * 64;

  for (int r = item0 + rg; r < item0 + 64; r += 8) {
    if (r >= n_items) break;
    const float4* er4 = reinterpret_cast<const float4*>(emb + (size_t)r * D);
    float4 acc = {0.f, 0.f, 0.f, 0.f};
#pragma unroll
    for (int k4 = 0; k4 < D / 4; ++k4) {
      const float4 e = er4[k4];
      const int kb = k4 * 4;
      {
        const float4 w = *reinterpret_cast<const float4*>(&Wlds[(kb + 0) * D + c4]);
        acc.x += e.x * w.x; acc.y += e.x * w.y; acc.z += e.x * w.z; acc.w += e.x * w.w;
      }
      {
        const float4 w = *reinterpret_cast<const float4*>(&Wlds[(kb + 1) * D + c4]);
        acc.x += e.y * w.x; acc.y += e.y * w.y; acc.z += e.y * w.z; acc.w += e.y * w.w;
      }
      {
        const float4 w = *reinterpret_cast<const float4*>(&Wlds[(kb + 2) * D + c4]);
        acc.x += e.z * w.x; acc.y += e.z * w.y; acc.z += e.z * w.z; acc.w += e.z * w.w;
      }
      {
        const float4 w = *reinterpret_cast<const float4*>(&Wlds[(kb + 3) * D + c4]);
        acc.x += e.w * w.x; acc.y += e.w * w.y; acc.z += e.w * w.z; acc.w += e.w * w.w;
      }
    }
    *reinterpret_cast<float4*>(P + (size_t)r * D + c4) = acc;
  }
}

// ---------------------------------------------------------------------------
// Kernel 2: histogram of destination rows.
// ---------------------------------------------------------------------------
__global__ __launch_bounds__(256) void hist_kernel(
    const int* __restrict__ rows, int* __restrict__ counts, int n_edges) {
  const int e = blockIdx.x * blockDim.x + threadIdx.x;
  if (e < n_edges) atomicAdd(&counts[rows[e]], 1);
}

// ---------------------------------------------------------------------------
// Kernel 3: single-block exclusive scan (Hillis-Steele per 1024-chunk with
// running carry). Writes row_start[0..n] and cursor[0..n-1] (= row_start).
// ---------------------------------------------------------------------------
__global__ __launch_bounds__(1024) void scan_kernel(
    const int* __restrict__ counts, int* __restrict__ row_start,
    int* __restrict__ cursor, int n_users) {
  __shared__ int lds[1024];
  const int tid = threadIdx.x;
  int offset = 0;
  for (int base = 0; base < n_users; base += 1024) {
    const int i = base + tid;
    const int x = (i < n_users) ? counts[i] : 0;
    lds[tid] = x;
    __syncthreads();
    for (int s = 1; s < 1024; s <<= 1) {
      const int y = (tid >= s) ? lds[tid - s] : 0;
      __syncthreads();
      lds[tid] += y;
      __syncthreads();
    }
    const int incl = lds[tid];
    const int total = lds[1023];
    if (i < n_users) {
      const int excl = offset + incl - x;
      row_start[i] = excl;
      cursor[i] = excl;
    }
    offset += total;
    __syncthreads();  // protect lds before next chunk overwrites
  }
  if (tid == 0) row_start[n_users] = offset;
}

// ---------------------------------------------------------------------------
// Kernel 4: bucket-fill edges into CSR order.
// ---------------------------------------------------------------------------
__global__ __launch_bounds__(256) void fill_kernel(
    const int* __restrict__ rows, const int* __restrict__ cols,
    const float* __restrict__ vals, int* __restrict__ cursor,
    int* __restrict__ col_sorted, float* __restrict__ val_sorted, int n_edges) {
  const int e = blockIdx.x * blockDim.x + threadIdx.x;
  if (e >= n_edges) return;
  const int pos = atomicAdd(&cursor[rows[e]], 1);
  col_sorted[pos] = cols[e];
  val_sorted[pos] = vals[e];
}

// ---------------------------------------------------------------------------
// Kernel 5: per-user gather-accumulate. 32 lanes per user, float4 each.
// out[u] = nj[u] * sum_j val[j] * P[col[j]]
// ---------------------------------------------------------------------------
__global__ __launch_bounds__(256) void gather_kernel(
    const float* __restrict__ P, const int* __restrict__ row_start,
    const int* __restrict__ col_sorted, const float* __restrict__ val_sorted,
    const float* __restrict__ nj, float* __restrict__ out, int n_users) {
  const long long tid = (long long)blockIdx.x * blockDim.x + threadIdx.x;
  const int u = (int)(tid >> 5);
  if (u >= n_users) return;
  const int lane = (int)(tid & 31);

  const int jbeg = row_start[u];
  const int jend = row_start[u + 1];
  float4 acc = {0.f, 0.f, 0.f, 0.f};
  for (int j = jbeg; j < jend; ++j) {
    const int c = col_sorted[j];
    const float v = val_sorted[j];
    const float4 p =
        *reinterpret_cast<const float4*>(P + (size_t)c * D + lane * 4);
    acc.x += v * p.x; acc.y += v * p.y; acc.z += v * p.z; acc.w += v * p.w;
  }
  const float s = nj[u];
  acc.x *= s; acc.y *= s; acc.z *= s; acc.w *= s;
  *reinterpret_cast<float4*>(out + (size_t)u * D + lane * 4) = acc;
}

extern "C" void kernel_launch(void* const* d_in, const int* in_sizes, int n_in,
                              void* d_out, int out_size, void* d_ws,
                              size_t ws_size, hipStream_t stream) {
  const float* item_emb = (const float*)d_in[0];  // [n_items, 128]
  const float* user_nj  = (const float*)d_in[1];  // [n_users, 1]
  const float* weight   = (const float*)d_in[2];  // [128, 128]
  const float* adj_vals = (const float*)d_in[3];  // [E]
  const int*   adj_rows = (const int*)d_in[4];    // [E]
  const int*   adj_cols = (const int*)d_in[5];    // [E]

  const int n_items = in_sizes[0] / D;
  const int n_users = in_sizes[1];
  const int n_edges = in_sizes[3];
  float* out = (float*)d_out;

  // ---- workspace layout (256B-aligned) ----
  auto align256 = [](size_t x) { return (x + 255) & ~(size_t)255; };
  char* ws = (char*)d_ws;
  size_t off = 0;
  float* P = (float*)(ws + off);           off = align256(off + (size_t)n_items * D * 4);
  int* counts = (int*)(ws + off);          off = align256(off + (size_t)n_users * 4);
  int* row_start = (int*)(ws + off);       off = align256(off + (size_t)(n_users + 1) * 4);
  int* cursor = (int*)(ws + off);          off = align256(off + (size_t)n_users * 4);
  int* col_sorted = (int*)(ws + off);      off = align256(off + (size_t)n_edges * 4);
  float* val_sorted = (float*)(ws + off);  off = align256(off + (size_t)n_edges * 4);

  // 1) P = item_emb @ W
  pw_kernel<<<(n_items + 63) / 64, 256, 0, stream>>>(item_emb, weight, P,
                                                     n_items);

  // 2) histogram of rows
  hipMemsetAsync(counts, 0, (size_t)n_users * 4, stream);
  hist_kernel<<<(n_edges + 255) / 256, 256, 0, stream>>>(adj_rows, counts,
                                                         n_edges);

  // 3) exclusive scan -> row_start, cursor
  scan_kernel<<<1, 1024, 0, stream>>>(counts, row_start, cursor, n_users);

  // 4) bucket-fill CSR
  fill_kernel<<<(n_edges + 255) / 256, 256, 0, stream>>>(
      adj_rows, adj_cols, adj_vals, cursor, col_sorted, val_sorted, n_edges);

  // 5) per-user gather (writes every output row -> no memset needed)
  {
    const long long total_threads = (long long)n_users * 32;
    const int blocks = (int)((total_threads + 255) / 256);
    gather_kernel<<<blocks, 256, 0, stream>>>(P, row_start, col_sorted,
                                              val_sorted, user_nj, out,
                                              n_users);
  }
}

// Round 3
// 351.630 us; speedup vs baseline: 8.0307x; 1.7210x over previous
//
#include <hip/hip_runtime.h>
#include <hip/hip_bf16.h>

#define D 128  // EMBED == LAYER == 128

// ---------------------------------------------------------------------------
// Kernel 1: P = item_emb @ W  — register-tiled SGEMM.
// Block = 256 threads (16x16), M-tile = 128 rows, N = K = 128 (whole).
// A staged in LDS (row-major, +4 pad for bank spread & 16B align), W in LDS.
// Each thread computes an 8x8 micro-tile.
// ---------------------------------------------------------------------------
__global__ __launch_bounds__(256) void pw_kernel(
    const float* __restrict__ emb, const float* __restrict__ W,
    float* __restrict__ P, int n_items) {
  __shared__ float Al[128][132];   // 67.6 KB (pad 4 floats: 528B row stride)
  __shared__ float Wl[128][128];   // 64 KB
  const int tid = threadIdx.x;
  const int m0 = blockIdx.x * 128;

  // cooperative load W (16384 floats = 16 float4/thread)
  {
    const float4* W4 = reinterpret_cast<const float4*>(W);
    float4* Wl4 = reinterpret_cast<float4*>(&Wl[0][0]);
#pragma unroll
    for (int i = 0; i < 16; ++i) Wl4[tid + 256 * i] = W4[tid + 256 * i];
  }
  // cooperative load A tile: 128 rows x 128 floats, coalesced float4s
  {
    const float4* E4 = reinterpret_cast<const float4*>(emb);
#pragma unroll
    for (int i = 0; i < 16; ++i) {
      const int f = tid + 256 * i;       // float4 index within tile
      const int row = f >> 5;            // 32 float4 per row
      const int c4 = (f & 31) * 4;
      const int r = m0 + row;
      float4 v = {0.f, 0.f, 0.f, 0.f};
      if (r < n_items) v = E4[(size_t)r * 32 + (f & 31)];
      *reinterpret_cast<float4*>(&Al[row][c4]) = v;
    }
  }
  __syncthreads();

  const int tx = tid & 15;   // owns 8 consecutive output cols
  const int ty = tid >> 4;   // owns 8 consecutive rows
  const int c0 = tx * 8;
  const int r0 = ty * 8;

  float acc[8][8];
#pragma unroll
  for (int i = 0; i < 8; ++i)
#pragma unroll
    for (int j = 0; j < 8; ++j) acc[i][j] = 0.f;

  for (int k = 0; k < D; ++k) {
    float a[8];
#pragma unroll
    for (int i = 0; i < 8; ++i) a[i] = Al[r0 + i][k];
    const float4 w0 = *reinterpret_cast<const float4*>(&Wl[k][c0]);
    const float4 w1 = *reinterpret_cast<const float4*>(&Wl[k][c0 + 4]);
#pragma unroll
    for (int i = 0; i < 8; ++i) {
      acc[i][0] += a[i] * w0.x; acc[i][1] += a[i] * w0.y;
      acc[i][2] += a[i] * w0.z; acc[i][3] += a[i] * w0.w;
      acc[i][4] += a[i] * w1.x; acc[i][5] += a[i] * w1.y;
      acc[i][6] += a[i] * w1.z; acc[i][7] += a[i] * w1.w;
    }
  }

#pragma unroll
  for (int i = 0; i < 8; ++i) {
    const int r = m0 + r0 + i;
    if (r < n_items) {
      float4 o0 = {acc[i][0], acc[i][1], acc[i][2], acc[i][3]};
      float4 o1 = {acc[i][4], acc[i][5], acc[i][6], acc[i][7]};
      *reinterpret_cast<float4*>(P + (size_t)r * D + c0) = o0;
      *reinterpret_cast<float4*>(P + (size_t)r * D + c0 + 4) = o1;
    }
  }
}

// ---------------------------------------------------------------------------
// Kernel 2: histogram of destination rows.
// ---------------------------------------------------------------------------
__global__ __launch_bounds__(256) void hist_kernel(
    const int* __restrict__ rows, int* __restrict__ counts, int n_edges) {
  const int e = blockIdx.x * blockDim.x + threadIdx.x;
  if (e < n_edges) atomicAdd(&counts[rows[e]], 1);
}

// ---------------------------------------------------------------------------
// Scan (multi-block): K_a block sums -> K_b scan partials -> K_c local scan.
// ---------------------------------------------------------------------------
__global__ __launch_bounds__(1024) void blocksum_kernel(
    const int* __restrict__ counts, int* __restrict__ partials, int n) {
  __shared__ int lds[1024];
  const int tid = threadIdx.x;
  const int i = blockIdx.x * 1024 + tid;
  lds[tid] = (i < n) ? counts[i] : 0;
  __syncthreads();
  for (int s = 512; s > 0; s >>= 1) {
    if (tid < s) lds[tid] += lds[tid + s];
    __syncthreads();
  }
  if (tid == 0) partials[blockIdx.x] = lds[0];
}

__global__ __launch_bounds__(1024) void scanpart_kernel(
    const int* __restrict__ partials, int* __restrict__ blockoff, int nb,
    int* __restrict__ row_start, int n_users, int n_edges) {
  __shared__ int lds[1024];
  const int tid = threadIdx.x;
  const int x = (tid < nb) ? partials[tid] : 0;
  lds[tid] = x;
  __syncthreads();
  for (int s = 1; s < 1024; s <<= 1) {
    const int y = (tid >= s) ? lds[tid - s] : 0;
    __syncthreads();
    lds[tid] += y;
    __syncthreads();
  }
  if (tid < nb) blockoff[tid] = lds[tid] - x;  // exclusive
  if (tid == 0) row_start[n_users] = n_edges;  // total is known
}

__global__ __launch_bounds__(1024) void localscan_kernel(
    const int* __restrict__ counts, const int* __restrict__ blockoff,
    int* __restrict__ row_start, int* __restrict__ cursor, int n) {
  __shared__ int lds[1024];
  const int tid = threadIdx.x;
  const int i = blockIdx.x * 1024 + tid;
  const int x = (i < n) ? counts[i] : 0;
  lds[tid] = x;
  __syncthreads();
  for (int s = 1; s < 1024; s <<= 1) {
    const int y = (tid >= s) ? lds[tid - s] : 0;
    __syncthreads();
    lds[tid] += y;
    __syncthreads();
  }
  if (i < n) {
    const int excl = blockoff[blockIdx.x] + lds[tid] - x;
    row_start[i] = excl;
    cursor[i] = excl;
  }
}

// ---------------------------------------------------------------------------
// Kernel 4: bucket-fill edges into CSR order.
// ---------------------------------------------------------------------------
__global__ __launch_bounds__(256) void fill_kernel(
    const int* __restrict__ rows, const int* __restrict__ cols,
    const float* __restrict__ vals, int* __restrict__ cursor,
    int* __restrict__ col_sorted, float* __restrict__ val_sorted, int n_edges) {
  const int e = blockIdx.x * blockDim.x + threadIdx.x;
  if (e >= n_edges) return;
  const int pos = atomicAdd(&cursor[rows[e]], 1);
  col_sorted[pos] = cols[e];
  val_sorted[pos] = vals[e];
}

// ---------------------------------------------------------------------------
// Kernel 5: per-user gather-accumulate. 32 lanes per user, float4 each.
// out[u] = nj[u] * sum_j val[j] * P[col[j]]
// ---------------------------------------------------------------------------
__global__ __launch_bounds__(256) void gather_kernel(
    const float* __restrict__ P, const int* __restrict__ row_start,
    const int* __restrict__ col_sorted, const float* __restrict__ val_sorted,
    const float* __restrict__ nj, float* __restrict__ out, int n_users) {
  const long long tid = (long long)blockIdx.x * blockDim.x + threadIdx.x;
  const int u = (int)(tid >> 5);
  if (u >= n_users) return;
  const int lane = (int)(tid & 31);

  const int jbeg = row_start[u];
  const int jend = row_start[u + 1];
  float4 acc = {0.f, 0.f, 0.f, 0.f};
  for (int j = jbeg; j < jend; ++j) {
    const int c = col_sorted[j];
    const float v = val_sorted[j];
    const float4 p =
        *reinterpret_cast<const float4*>(P + (size_t)c * D + lane * 4);
    acc.x += v * p.x; acc.y += v * p.y; acc.z += v * p.z; acc.w += v * p.w;
  }
  const float s = nj[u];
  acc.x *= s; acc.y *= s; acc.z *= s; acc.w *= s;
  *reinterpret_cast<float4*>(out + (size_t)u * D + lane * 4) = acc;
}

extern "C" void kernel_launch(void* const* d_in, const int* in_sizes, int n_in,
                              void* d_out, int out_size, void* d_ws,
                              size_t ws_size, hipStream_t stream) {
  const float* item_emb = (const float*)d_in[0];  // [n_items, 128]
  const float* user_nj  = (const float*)d_in[1];  // [n_users, 1]
  const float* weight   = (const float*)d_in[2];  // [128, 128]
  const float* adj_vals = (const float*)d_in[3];  // [E]
  const int*   adj_rows = (const int*)d_in[4];    // [E]
  const int*   adj_cols = (const int*)d_in[5];    // [E]

  const int n_items = in_sizes[0] / D;
  const int n_users = in_sizes[1];
  const int n_edges = in_sizes[3];
  float* out = (float*)d_out;

  const int nb = (n_users + 1023) / 1024;  // scan blocks

  // ---- workspace layout (256B-aligned) ----
  auto align256 = [](size_t x) { return (x + 255) & ~(size_t)255; };
  char* ws = (char*)d_ws;
  size_t off = 0;
  float* P = (float*)(ws + off);           off = align256(off + (size_t)n_items * D * 4);
  int* counts = (int*)(ws + off);          off = align256(off + (size_t)n_users * 4);
  int* row_start = (int*)(ws + off);       off = align256(off + (size_t)(n_users + 1) * 4);
  int* cursor = (int*)(ws + off);          off = align256(off + (size_t)n_users * 4);
  int* col_sorted = (int*)(ws + off);      off = align256(off + (size_t)n_edges * 4);
  float* val_sorted = (float*)(ws + off);  off = align256(off + (size_t)n_edges * 4);
  int* partials = (int*)(ws + off);        off = align256(off + (size_t)nb * 4);
  int* blockoff = (int*)(ws + off);        off = align256(off + (size_t)nb * 4);

  // 1) P = item_emb @ W
  pw_kernel<<<(n_items + 127) / 128, 256, 0, stream>>>(item_emb, weight, P,
                                                       n_items);

  // 2) histogram of rows
  hipMemsetAsync(counts, 0, (size_t)n_users * 4, stream);
  hist_kernel<<<(n_edges + 255) / 256, 256, 0, stream>>>(adj_rows, counts,
                                                         n_edges);

  // 3) multi-block exclusive scan -> row_start, cursor
  blocksum_kernel<<<nb, 1024, 0, stream>>>(counts, partials, n_users);
  scanpart_kernel<<<1, 1024, 0, stream>>>(partials, blockoff, nb, row_start,
                                          n_users, n_edges);
  localscan_kernel<<<nb, 1024, 0, stream>>>(counts, blockoff, row_start,
                                            cursor, n_users);

  // 4) bucket-fill CSR
  fill_kernel<<<(n_edges + 255) / 256, 256, 0, stream>>>(
      adj_rows, adj_cols, adj_vals, cursor, col_sorted, val_sorted, n_edges);

  // 5) per-user gather (writes every output row -> no memset needed)
  {
    const long long total_threads = (long long)n_users * 32;
    const int blocks = (int)((total_threads + 255) / 256);
    gather_kernel<<<blocks, 256, 0, stream>>>(P, row_start, col_sorted,
                                              val_sorted, user_nj, out,
                                              n_users);
  }
}